// Round 4
// baseline (395.493 us; speedup 1.0000x reference)
//
#include <hip/hip_runtime.h>
#include <hip/hip_bf16.h>
#include <stdint.h>

#define OUT_DIM 8192
#define IN_DIM  8192
#define GS      128
#define MROWS   32
#define NSPLIT  8          // split-K chunks of 1024
#define PART_ELEMS (MROWS * OUT_DIM)
#define NPACK (OUT_DIM * IN_DIM / 16)   // 4M packed dwords (16 weights each)

typedef __attribute__((ext_vector_type(8))) short bf16x8;   // MFMA A/B frag (4 VGPR)
typedef __attribute__((ext_vector_type(4))) float f32x4;    // MFMA C/D frag
typedef __attribute__((ext_vector_type(8))) unsigned short u16x8;

__device__ __forceinline__ unsigned short f2bf_rne(float f) {
    uint32_t v = __builtin_bit_cast(uint32_t, f);
    v += 0x7FFFu + ((v >> 16) & 1u);
    return (unsigned short)(v >> 16);
}

// x (32x8192 fp32) -> bf16 workspace. 262144 elems, 8/thread, 128 blocks.
__global__ __launch_bounds__(256) void prep_xbf(const float* __restrict__ x,
                                                unsigned short* __restrict__ xbf) {
    int i = (blockIdx.x * 256 + threadIdx.x) * 8;
    float4 a = *(const float4*)(x + i);
    float4 b = *(const float4*)(x + i + 4);
    float f[8] = {a.x, a.y, a.z, a.w, b.x, b.y, b.z, b.w};
    u16x8 u;
#pragma unroll
    for (int j = 0; j < 8; ++j) u[j] = f2bf_rne(f[j]);
    *(u16x8*)(xbf + i) = u;
}

// 256 MB int32 ternary -> 16 MB 2-bit packed, o-tile-interleaved:
// packed[T*8192 + kd*16 + r] bits [2j+1:2j] = tern[(T*16+r)*8192 + kd*16 + j] & 3
// (0b00 = 0, 0b01 = +1, 0b11 = -1; bit0 = nonzero, bit1 = sign)
__global__ __launch_bounds__(256) void compress_w(const int* __restrict__ tern,
                                                  uint32_t* __restrict__ packed) {
    const int g  = blockIdx.x * 256 + threadIdx.x;   // 0 .. 4M-1
    const int r  = g & 15;
    const int kd = (g >> 4) & 511;
    const int T  = g >> 13;
    const int* src = tern + (size_t)(T * 16 + r) * IN_DIM + kd * 16;
    int4 w0 = *(const int4*)(src);
    int4 w1 = *(const int4*)(src + 4);
    int4 w2 = *(const int4*)(src + 8);
    int4 w3 = *(const int4*)(src + 12);
    int w[16] = {w0.x, w0.y, w0.z, w0.w, w1.x, w1.y, w1.z, w1.w,
                 w2.x, w2.y, w2.z, w2.w, w3.x, w3.y, w3.z, w3.w};
    uint32_t acc = 0;
#pragma unroll
    for (int j = 0; j < 16; ++j) acc |= ((uint32_t)w[j] & 3u) << (2 * j);
    packed[g] = acc;   // fully coalesced (g-linear)
}

// part[kc][t][o] = sum_{k in chunk kc} x[t][k] * w[o][k]
// Wave: 16 o-cols x 32 t-rows (two 16x16x32 bf16 MFMA accs), K-chunk 1024.
// Weights from 2-bit packed: per it, wave reads 4 full 128-B lines (broadcast x2).
__global__ __launch_bounds__(256) void ternary_gemm(
    const uint32_t* __restrict__ packed, const float* __restrict__ scales,
    const unsigned short* __restrict__ xbf, float* __restrict__ part) {
    const int wave  = blockIdx.x * 4 + (threadIdx.x >> 6);
    const int lane  = threadIdx.x & 63;
    const int kc    = wave >> 9;     // 0..7   split-K chunk
    const int T     = wave & 511;    // 0..511 o-tile
    const int n     = lane & 15;
    const int quad  = lane >> 4;
    const int hsh   = lane & 16;          // (quad&1)*16 : which 16-bit half
    const int qh    = (lane >> 5) & 1;    // quad>>1     : which dword pair
    const int o     = (T << 4) + n;
    const int k0base = kc << 10;

    const uint32_t* __restrict__ wp =
        packed + (size_t)T * 8192 + kc * 1024 + qh * 16 + n;
    const unsigned short* __restrict__ xr0 = xbf + n * IN_DIM;
    const unsigned short* __restrict__ xr1 = xbf + (16 + n) * IN_DIM;

    const float* __restrict__ sp = scales + o * (IN_DIM / GS) + (kc << 3);
    float s_cur = sp[0];

    f32x4 acc0 = {0.f, 0.f, 0.f, 0.f};
    f32x4 acc1 = {0.f, 0.f, 0.f, 0.f};

#pragma unroll 1   // keep outer loop rolled (VGPR budget)
    for (int it = 0; it < 8; ++it) {
        const uint32_t p = f2bf_rne(s_cur);          // +bf16(s), sign-free
        float s_nxt = sp[(it < 7) ? (it + 1) : 7];   // pipeline scale 1 it ahead
        const int k0 = k0base + (it << 7);
        const uint32_t* __restrict__ wit = wp + (it << 7);
#pragma unroll
        for (int st = 0; st < 4; ++st) {
            const uint32_t dw = wit[st << 5];        // one 128-B line / wave
            const uint32_t c  = dw >> hsh;           // this lane's 8 weights (16b)
            const int k = k0 + (st << 5) + (quad << 3);
            bf16x8 a0 = *(const bf16x8*)(xr0 + k);
            bf16x8 a1 = *(const bf16x8*)(xr1 + k);
            bf16x8 bfr;
#pragma unroll
            for (int j = 0; j < 8; ++j) {
                uint32_t bits = (c >> (2 * j)) & 3u;
                // bit0 = nonzero, bit1 = sign; p > 0 so sign-or is exact
                uint32_t v = (p | ((bits & 2u) << 14)) & (0u - (bits & 1u));
                bfr[j] = (short)v;
            }
            acc0 = __builtin_amdgcn_mfma_f32_16x16x32_bf16(a0, bfr, acc0, 0, 0, 0);
            acc1 = __builtin_amdgcn_mfma_f32_16x16x32_bf16(a1, bfr, acc1, 0, 0, 0);
        }
        s_cur = s_nxt;
    }

    // D layout: col = lane&15 (=o), row t = quad*4 + reg. Plain stores.
    float* __restrict__ prow = part + (size_t)kc * PART_ELEMS;
#pragma unroll
    for (int r = 0; r < 4; ++r) {
        prow[(quad * 4 + r) * OUT_DIM + o]        = acc0[r];
        prow[(quad * 4 + r + 16) * OUT_DIM + o]   = acc1[r];
    }
}

// out = sum over 8 split-K partials. 256 blocks x 256 thr x float4.
__global__ __launch_bounds__(256) void reduce_parts(const float* __restrict__ part,
                                                    float* __restrict__ out) {
    const int i = (blockIdx.x * 256 + threadIdx.x) * 4;
    float4 s = *(const float4*)(part + i);
#pragma unroll
    for (int kc = 1; kc < NSPLIT; ++kc) {
        float4 v = *(const float4*)(part + (size_t)kc * PART_ELEMS + i);
        s.x += v.x; s.y += v.y; s.z += v.z; s.w += v.w;
    }
    *(float4*)(out + i) = s;
}

extern "C" void kernel_launch(void* const* d_in, const int* in_sizes, int n_in,
                              void* d_out, int out_size, void* d_ws, size_t ws_size,
                              hipStream_t stream) {
    const float* x      = (const float*)d_in[0];
    const int*   tern   = (const int*)d_in[1];
    const float* scales = (const float*)d_in[2];
    float* out = (float*)d_out;

    unsigned short* xbf = (unsigned short*)d_ws;                 // 512 KB @ 0
    float* part   = (float*)((char*)d_ws + (1u << 20));          // 8 MB  @ 1 MB
    uint32_t* pkd = (uint32_t*)((char*)d_ws + (16u << 20));      // 16 MB @ 16 MB

    prep_xbf<<<128, 256, 0, stream>>>(x, xbf);
    compress_w<<<NPACK / 256, 256, 0, stream>>>(tern, pkd);
    ternary_gemm<<<1024, 256, 0, stream>>>(pkd, scales, xbf, part);
    reduce_parts<<<256, 256, 0, stream>>>(part, out);
}